// Round 10
// baseline (696.840 us; speedup 1.0000x reference)
//
#include <hip/hip_runtime.h>
#include <hip/hip_bf16.h>

// MultiHeadSelfAttention (CogView PB-Relax) for B=2, S=2048, D=1024, H=16, Dh=64.
// PB-Relax softmax == plain softmax(scores - rowmax) => flash-style online softmax.
// Plan: (1) QKV bf16-MFMA GEMM (fp32 inputs converted on the fly), v stored transposed.
//       (2) flash attention, both batches per block so the 256MB bias is read once.
//       Bias is read-once => nontemporal loads (don't evict the reused K/V from L2/L3).

typedef __bf16 bf16x8 __attribute__((ext_vector_type(8)));
typedef float f32x4 __attribute__((ext_vector_type(4)));

#define MFMA16(a, b, c) __builtin_amdgcn_mfma_f32_16x16x32_bf16(a, b, c, 0, 0, 0)

// A-frag (16x32): lane holds A[row = lane&15][k = (lane>>4)*8 + i], i=0..7 (16B contig)
// B-frag (32x16): lane holds B[k = (lane>>4)*8 + i][col = lane&15]  (load from row-major
//                 "B^T" source as 16B contig along k)
// C/D     (16x16): lane holds C[row = (lane>>4)*4 + j][col = lane&15], j=0..3 (verified m89/m91)

// ---------------------------------------------------------------------------
// Kernel 1: q/k/v = x @ W^T + b, output bf16. q,k: [B][H][S][64]; v: [B][H][64][S]
// ---------------------------------------------------------------------------
__global__ __launch_bounds__(256) void qkv_gemm_kernel(
    const float* __restrict__ x,
    const float* __restrict__ Wq, const float* __restrict__ bq,
    const float* __restrict__ Wk, const float* __restrict__ bk,
    const float* __restrict__ Wv, const float* __restrict__ bvec,
    __bf16* __restrict__ qo, __bf16* __restrict__ ko, __bf16* __restrict__ vto)
{
    // tile: 128x128, BK=64. LDS stride 72 bf16 (144B, 16B-aligned, ~2-way banks)
    __shared__ __bf16 As[128][72];
    __shared__ __bf16 Bs[128][72];

    const int im   = blockIdx.x;          // 0..31 over M=4096
    const int iw   = blockIdx.y;          // 0..23: 3 matrices x 8 col-tiles
    const int wsel = iw >> 3;             // 0=q 1=k 2=v
    const int ncol = (iw & 7) << 7;

    const float* W  = (wsel == 0) ? Wq : (wsel == 1) ? Wk : Wv;
    const float* bb = (wsel == 0) ? bq : (wsel == 1) ? bk : bvec;

    const int tid  = threadIdx.x;
    const int wave = tid >> 6, lane = tid & 63;
    const int l15  = lane & 15, lg = lane >> 4;
    const int wr   = (wave >> 1) << 6;    // wave row offset in tile
    const int wc   = (wave & 1) << 6;    // wave col offset

    const int i0   = im << 7;
    const int srow = tid >> 1;            // staging: 2 threads per row
    const int skof = (tid & 1) << 5;      // 32 floats each

    f32x4 acc[4][4];
#pragma unroll
    for (int a = 0; a < 4; a++)
#pragma unroll
        for (int b = 0; b < 4; b++) acc[a][b] = f32x4{0.f, 0.f, 0.f, 0.f};

    const float4* ap = (const float4*)(x + (size_t)(i0 + srow) * 1024 + skof);
    const float4* bp = (const float4*)(W + (size_t)(ncol + srow) * 1024 + skof);

    for (int kb = 0; kb < 1024; kb += 64) {
        float4 av[8], bv[8];
#pragma unroll
        for (int u = 0; u < 8; u++) { av[u] = ap[u]; bv[u] = bp[u]; }
        ap += 16; bp += 16;

        __syncthreads();
#pragma unroll
        for (int u = 0; u < 4; u++) {
            float4 v0 = av[2 * u], v1 = av[2 * u + 1];
            bf16x8 t;
            t[0] = (__bf16)v0.x; t[1] = (__bf16)v0.y; t[2] = (__bf16)v0.z; t[3] = (__bf16)v0.w;
            t[4] = (__bf16)v1.x; t[5] = (__bf16)v1.y; t[6] = (__bf16)v1.z; t[7] = (__bf16)v1.w;
            *(bf16x8*)&As[srow][skof + u * 8] = t;
            float4 w0 = bv[2 * u], w1 = bv[2 * u + 1];
            bf16x8 s;
            s[0] = (__bf16)w0.x; s[1] = (__bf16)w0.y; s[2] = (__bf16)w0.z; s[3] = (__bf16)w0.w;
            s[4] = (__bf16)w1.x; s[5] = (__bf16)w1.y; s[6] = (__bf16)w1.z; s[7] = (__bf16)w1.w;
            *(bf16x8*)&Bs[srow][skof + u * 8] = s;
        }
        __syncthreads();

#pragma unroll
        for (int ks = 0; ks < 2; ks++) {
            bf16x8 af[4], bf[4];
#pragma unroll
            for (int mi = 0; mi < 4; mi++)
                af[mi] = *(const bf16x8*)&As[wr + mi * 16 + l15][ks * 32 + lg * 8];
#pragma unroll
            for (int ni = 0; ni < 4; ni++)
                bf[ni] = *(const bf16x8*)&Bs[wc + ni * 16 + l15][ks * 32 + lg * 8];
#pragma unroll
            for (int mi = 0; mi < 4; mi++)
#pragma unroll
                for (int ni = 0; ni < 4; ni++)
                    acc[mi][ni] = MFMA16(af[mi], bf[ni], acc[mi][ni]);
        }
    }

    // epilogue: C layout row=(lane>>4)*4+j, col=lane&15
#pragma unroll
    for (int ni = 0; ni < 4; ni++) {
        const int o  = ncol + wc + ni * 16 + l15;
        const float bo = bb[o];
        const int h = o >> 6, d = o & 63;
#pragma unroll
        for (int mi = 0; mi < 4; mi++) {
#pragma unroll
            for (int j = 0; j < 4; j++) {
                const int i  = i0 + wr + mi * 16 + lg * 4 + j;
                const int bi = i >> 11, s = i & 2047;
                const float val = acc[mi][ni][j] + bo;
                if (wsel < 2) {
                    __bf16* dst = (wsel == 0) ? qo : ko;
                    dst[((size_t)((bi * 16 + h) * 2048 + s)) * 64 + d] = (__bf16)val;
                } else {
                    vto[((size_t)((bi * 16 + h) * 64 + d)) * 2048 + s] = (__bf16)val;
                }
            }
        }
    }
}

// ---------------------------------------------------------------------------
// Kernel 2: flash attention. grid (32 q-tiles, 16 heads), 4 waves x 16 q-rows,
// both batches inside the block (bias registers reused).
// ---------------------------------------------------------------------------
__global__ __launch_bounds__(256) void attn_kernel(
    const __bf16* __restrict__ qg,   // [B][H][S][64]
    const __bf16* __restrict__ kg,   // [B][H][S][64]
    const __bf16* __restrict__ vtg,  // [B][H][64][S]
    const float* __restrict__ bias,  // [H][S][S]
    const int* __restrict__ mask,    // [B][S]
    float* __restrict__ out)         // [B][S][H*64]
{
    __shared__ __bf16 P[4][16][72];  // wave-private P tiles (16 q x 64 k), padded

    const int qt = blockIdx.x, h = blockIdx.y;
    const int wave = threadIdx.x >> 6, lane = threadIdx.x & 63;
    const int l15 = lane & 15, lg = lane >> 4;
    const int qbase = qt * 64 + wave * 16;

    // Q fragments, both batches, 2 d-slices (hoisted)
    bf16x8 qf[2][2];
#pragma unroll
    for (int b = 0; b < 2; b++)
#pragma unroll
        for (int dsl = 0; dsl < 2; dsl++)
            qf[b][dsl] = *(const bf16x8*)(qg +
                ((size_t)((b * 16 + h) * 2048 + qbase + l15)) * 64 + dsl * 32 + lg * 8);

    f32x4 acc[2][4];
    float m[2][4], l[2][4];
#pragma unroll
    for (int b = 0; b < 2; b++) {
#pragma unroll
        for (int dt = 0; dt < 4; dt++) acc[b][dt] = f32x4{0.f, 0.f, 0.f, 0.f};
#pragma unroll
        for (int j = 0; j < 4; j++) { m[b][j] = -1e30f; l[b][j] = 0.f; }
    }

    const float* biasrow = bias + ((size_t)h * 2048 + qbase + lg * 4) * 2048;
    const int* mrow0 = mask;
    const int* mrow1 = mask + 2048;

    for (int kt = 0; kt < 32; kt++) {
        const int kbase = kt * 64;

        // bias tile in C-fragment layout, shared by both batches.
        // read-once stream => nontemporal (keep K/V resident in L2/L3)
        float bfr[4][4];
#pragma unroll
        for (int t = 0; t < 4; t++)
#pragma unroll
            for (int j = 0; j < 4; j++)
                bfr[t][j] = __builtin_nontemporal_load(
                    &biasrow[(size_t)j * 2048 + kbase + t * 16 + l15]);

        float madd[2][4];
#pragma unroll
        for (int t = 0; t < 4; t++) {
            madd[0][t] = mrow0[kbase + t * 16 + l15] ? 0.f : -1e38f;
            madd[1][t] = mrow1[kbase + t * 16 + l15] ? 0.f : -1e38f;
        }

#pragma unroll
        for (int b = 0; b < 2; b++) {
            const __bf16* kbp = kg + ((size_t)((b * 16 + h) * 2048 + kbase)) * 64;

            f32x4 sv[4];
#pragma unroll
            for (int t = 0; t < 4; t++) {
                bf16x8 kf0 = *(const bf16x8*)(kbp + (t * 16 + l15) * 64 + lg * 8);
                bf16x8 kf1 = *(const bf16x8*)(kbp + (t * 16 + l15) * 64 + 32 + lg * 8);
                f32x4 c = f32x4{0.f, 0.f, 0.f, 0.f};
                c = MFMA16(qf[b][0], kf0, c);
                c = MFMA16(qf[b][1], kf1, c);
                sv[t] = c;
            }

            float s[4][4];
#pragma unroll
            for (int t = 0; t < 4; t++)
#pragma unroll
                for (int j = 0; j < 4; j++)
                    s[t][j] = (sv[t][j] + bfr[t][j]) * 0.125f + madd[b][t];

            // wave-parallel row max (rows live in 16-lane groups)
            float tm[4];
#pragma unroll
            for (int j = 0; j < 4; j++) {
                tm[j] = fmaxf(fmaxf(s[0][j], s[1][j]), fmaxf(s[2][j], s[3][j]));
                tm[j] = fmaxf(tm[j], __shfl_xor(tm[j], 1));
                tm[j] = fmaxf(tm[j], __shfl_xor(tm[j], 2));
                tm[j] = fmaxf(tm[j], __shfl_xor(tm[j], 4));
                tm[j] = fmaxf(tm[j], __shfl_xor(tm[j], 8));
            }

            float mn[4], cr[4];
#pragma unroll
            for (int j = 0; j < 4; j++) {
                mn[j] = fmaxf(m[b][j], tm[j]);
                cr[j] = __expf(m[b][j] - mn[j]);
                m[b][j] = mn[j];
            }

            float rs[4] = {0.f, 0.f, 0.f, 0.f};
#pragma unroll
            for (int t = 0; t < 4; t++)
#pragma unroll
                for (int j = 0; j < 4; j++) {
                    float p = __expf(s[t][j] - mn[j]);
                    rs[j] += p;
                    P[wave][lg * 4 + j][t * 16 + l15] = (__bf16)p;
                }
#pragma unroll
            for (int j = 0; j < 4; j++) {
                rs[j] += __shfl_xor(rs[j], 1);
                rs[j] += __shfl_xor(rs[j], 2);
                rs[j] += __shfl_xor(rs[j], 4);
                rs[j] += __shfl_xor(rs[j], 8);
                l[b][j] = l[b][j] * cr[j] + rs[j];
            }

#pragma unroll
            for (int dt = 0; dt < 4; dt++)
#pragma unroll
                for (int j = 0; j < 4; j++) acc[b][dt][j] *= cr[j];

            // PV: A = P (from LDS, A-layout), B = V^T rows (16B contig along k)
            const __bf16* vbp = vtg + ((size_t)((b * 16 + h) * 64)) * 2048 + kbase;
#pragma unroll
            for (int ks2 = 0; ks2 < 2; ks2++) {
                bf16x8 pf = *(const bf16x8*)&P[wave][l15][ks2 * 32 + lg * 8];
#pragma unroll
                for (int dt = 0; dt < 4; dt++) {
                    bf16x8 vf = *(const bf16x8*)(vbp + (size_t)(dt * 16 + l15) * 2048 +
                                                 ks2 * 32 + lg * 8);
                    acc[b][dt] = MFMA16(pf, vf, acc[b][dt]);
                }
            }
        }
    }

    // epilogue: out[b][s][h*64+d] = acc / l (streaming write => nontemporal)
#pragma unroll
    for (int b = 0; b < 2; b++)
#pragma unroll
        for (int j = 0; j < 4; j++) {
            const float inv = 1.0f / l[b][j];
            const int s = qbase + lg * 4 + j;
            float* orow = out + ((size_t)(b * 2048 + s)) * 1024 + h * 64;
#pragma unroll
            for (int dt = 0; dt < 4; dt++)
                __builtin_nontemporal_store(acc[b][dt][j] * inv, &orow[dt * 16 + l15]);
        }
}

extern "C" void kernel_launch(void* const* d_in, const int* in_sizes, int n_in,
                              void* d_out, int out_size, void* d_ws, size_t ws_size,
                              hipStream_t stream)
{
    const float* x    = (const float*)d_in[0];
    const int*   msk  = (const int*)d_in[1];
    const float* ab   = (const float*)d_in[2];
    const float* Wq   = (const float*)d_in[3];
    const float* bq   = (const float*)d_in[4];
    const float* Wk   = (const float*)d_in[5];
    const float* bk   = (const float*)d_in[6];
    const float* Wv   = (const float*)d_in[7];
    const float* bv   = (const float*)d_in[8];

    const size_t per = (size_t)2 * 16 * 2048 * 64;  // 4.19M elems
    __bf16* qw = (__bf16*)d_ws;
    __bf16* kw = qw + per;
    __bf16* vw = kw + per;

    qkv_gemm_kernel<<<dim3(32, 24), 256, 0, stream>>>(x, Wq, bq, Wk, bk, Wv, bv, qw, kw, vw);
    attn_kernel<<<dim3(32, 16), 256, 0, stream>>>(qw, kw, vw, ab, msk, (float*)d_out);
}